// Round 10
// baseline (11359.439 us; speedup 1.0000x reference)
//
#include <hip/hip_runtime.h>

#define NPTS 16384
#define NB 4
#define MPER 4096
#define M_TOT 16384
#define CCH 32
#define HH1 128
#define HH2 256
#define HH3 256
#define KNB 33
#define NPAD 36
#define R2V (0.2f*0.2f)

// ws layout (bytes)
#define WS_IDX   0                    // 16384 int
#define WS_CNT   (WS_IDX + 65536)     // 16384 int
#define WS_NBR   (WS_CNT + 65536)     // 16384*36 int
#define WS_AGG   (WS_NBR + 2359296)   // 16384*256 f32

static __device__ __forceinline__ float get4(const float4& v, int j) {
  return j == 0 ? v.x : j == 1 ? v.y : j == 2 ? v.z : v.w;
}

#define FMA4(acc_, s_, w_) { (acc_).x += (s_)*(w_).x; (acc_).y += (s_)*(w_).y; (acc_).z += (s_)*(w_).z; (acc_).w += (s_)*(w_).w; }

// ---------------------------------------------------------------------------
// Kernel 1: farthest point sampling. One block per cloud, 512 threads,
// 32 points/thread in named float4s, LAUNDERED through opaque asm so the
// compiler cannot rematerialize the (loop-invariant) pos[] loads each
// iteration — r8/r9 showed it kept only mind[] in regs (VGPR=96) and
// re-loaded pos every one of the 4095 iterations. One barrier/iter,
// double-buffered LDS wave-partials, redundant 8-way reduce. Exact
// (non-FMA) distance math; argmax ties -> lowest global index.
// ---------------------------------------------------------------------------
__global__ __launch_bounds__(512, 2) void fps_kernel(const float* __restrict__ pos,
    int* __restrict__ idxg, float* __restrict__ posd, float* __restrict__ batchf) {
  const int b = blockIdx.x;
  const int t = threadIdx.x;
  const int base = b * NPTS;
  const int lane = t & 63, wv = t >> 6;
  __shared__ float bufV[2][8];
  __shared__ int   bufI[2][8];

  float4 px0, px1, px2, px3, px4, px5, px6, px7;
  float4 py0, py1, py2, py3, py4, py5, py6, py7;
  float4 pz0, pz1, pz2, pz3, pz4, pz5, pz6, pz7;
  float4 md0, md1, md2, md3, md4, md5, md6, md7;

#define LD1(C_, PX_, PY_, PZ_, I0_) { \
    int p_ = base + (I0_) + t; \
    PX_.C_ = pos[p_ * 3 + 0]; PY_.C_ = pos[p_ * 3 + 1]; PZ_.C_ = pos[p_ * 3 + 2]; }
#define LD4(PX_, PY_, PZ_, G_) \
    LD1(x, PX_, PY_, PZ_, ((G_)*4+0)*512) \
    LD1(y, PX_, PY_, PZ_, ((G_)*4+1)*512) \
    LD1(z, PX_, PY_, PZ_, ((G_)*4+2)*512) \
    LD1(w, PX_, PY_, PZ_, ((G_)*4+3)*512)

  LD4(px0, py0, pz0, 0) LD4(px1, py1, pz1, 1)
  LD4(px2, py2, pz2, 2) LD4(px3, py3, pz3, 3)
  LD4(px4, py4, pz4, 4) LD4(px5, py5, pz5, 5)
  LD4(px6, py6, pz6, 6) LD4(px7, py7, pz7, 7)

  // Opaque keep: values become asm outputs -> compiler must hold them in
  // VGPRs across the loop; it can no longer re-load pos[] per iteration.
#define KEEP4(V_) asm volatile("" : "+v"((V_).x), "+v"((V_).y), "+v"((V_).z), "+v"((V_).w));
  KEEP4(px0) KEEP4(px1) KEEP4(px2) KEEP4(px3)
  KEEP4(px4) KEEP4(px5) KEEP4(px6) KEEP4(px7)
  KEEP4(py0) KEEP4(py1) KEEP4(py2) KEEP4(py3)
  KEEP4(py4) KEEP4(py5) KEEP4(py6) KEEP4(py7)
  KEEP4(pz0) KEEP4(pz1) KEEP4(pz2) KEEP4(pz3)
  KEEP4(pz4) KEEP4(pz5) KEEP4(pz6) KEEP4(pz7)

  float nx = pos[base * 3 + 0], ny = pos[base * 3 + 1], nz = pos[base * 3 + 2];
  if (t == 0) {
    idxg[b * MPER] = base;
    posd[(b * MPER) * 3 + 0] = nx;
    posd[(b * MPER) * 3 + 1] = ny;
    posd[(b * MPER) * 3 + 2] = nz;
    batchf[b * MPER] = (float)b;
  }

  float bv = -1.0f; int bi = 0;

#define INI1(C_, PX_, PY_, PZ_, MD_, I0_) { \
    float dx_ = PX_.C_ - nx, dy_ = PY_.C_ - ny, dz_ = PZ_.C_ - nz; \
    float d2_ = __fadd_rn(__fadd_rn(__fmul_rn(dx_, dx_), __fmul_rn(dy_, dy_)), __fmul_rn(dz_, dz_)); \
    MD_.C_ = d2_; \
    if (d2_ > bv) { bv = d2_; bi = (I0_) + t; } }
#define INI4(PX_, PY_, PZ_, MD_, G_) \
    INI1(x, PX_, PY_, PZ_, MD_, ((G_)*4+0)*512) \
    INI1(y, PX_, PY_, PZ_, MD_, ((G_)*4+1)*512) \
    INI1(z, PX_, PY_, PZ_, MD_, ((G_)*4+2)*512) \
    INI1(w, PX_, PY_, PZ_, MD_, ((G_)*4+3)*512)

  INI4(px0, py0, pz0, md0, 0) INI4(px1, py1, pz1, md1, 1)
  INI4(px2, py2, pz2, md2, 2) INI4(px3, py3, pz3, md3, 3)
  INI4(px4, py4, pz4, md4, 4) INI4(px5, py5, pz5, md5, 5)
  INI4(px6, py6, pz6, md6, 6) INI4(px7, py7, pz7, md7, 7)

#pragma unroll
  for (int off = 32; off >= 1; off >>= 1) {
    float ov = __shfl_xor(bv, off, 64);
    int   oi = __shfl_xor(bi, off, 64);
    if (ov > bv || (ov == bv && oi < bi)) { bv = ov; bi = oi; }
  }

#define UPD1(C_, PX_, PY_, PZ_, MD_, I0_) { \
    float dx_ = PX_.C_ - nx, dy_ = PY_.C_ - ny, dz_ = PZ_.C_ - nz; \
    float d2_ = __fadd_rn(__fadd_rn(__fmul_rn(dx_, dx_), __fmul_rn(dy_, dy_)), __fmul_rn(dz_, dz_)); \
    float m_ = fminf(MD_.C_, d2_); MD_.C_ = m_; \
    if (m_ > bv) { bv = m_; bi = (I0_) + t; } }
#define UPD4(PX_, PY_, PZ_, MD_, G_) \
    UPD1(x, PX_, PY_, PZ_, MD_, ((G_)*4+0)*512) \
    UPD1(y, PX_, PY_, PZ_, MD_, ((G_)*4+1)*512) \
    UPD1(z, PX_, PY_, PZ_, MD_, ((G_)*4+2)*512) \
    UPD1(w, PX_, PY_, PZ_, MD_, ((G_)*4+3)*512)

  for (int m = 1; m < MPER; ++m) {
    if (lane == 0) { bufV[m & 1][wv] = bv; bufI[m & 1][wv] = bi; }
    __syncthreads();
    float v = bufV[m & 1][0]; int j = bufI[m & 1][0];
#pragma unroll
    for (int w = 1; w < 8; ++w) {
      float v2 = bufV[m & 1][w]; int j2 = bufI[m & 1][w];
      if (v2 > v || (v2 == v && j2 < j)) { v = v2; j = j2; }
    }
    nx = pos[(base + j) * 3 + 0];
    ny = pos[(base + j) * 3 + 1];
    nz = pos[(base + j) * 3 + 2];
    if (t == 0) {
      idxg[b * MPER + m] = base + j;
      posd[(b * MPER + m) * 3 + 0] = nx;
      posd[(b * MPER + m) * 3 + 1] = ny;
      posd[(b * MPER + m) * 3 + 2] = nz;
      batchf[b * MPER + m] = (float)b;
    }
    bv = -1.0f; bi = 0;
    UPD4(px0, py0, pz0, md0, 0) UPD4(px1, py1, pz1, md1, 1)
    UPD4(px2, py2, pz2, md2, 2) UPD4(px3, py3, pz3, md3, 3)
    UPD4(px4, py4, pz4, md4, 4) UPD4(px5, py5, pz5, md5, 5)
    UPD4(px6, py6, pz6, md6, 6) UPD4(px7, py7, pz7, md7, 7)
#pragma unroll
    for (int off = 32; off >= 1; off >>= 1) {
      float ov = __shfl_xor(bv, off, 64);
      int   oi = __shfl_xor(bi, off, 64);
      if (ov > bv || (ov == bv && oi < bi)) { bv = ov; bi = oi; }
    }
  }
}

// ---------------------------------------------------------------------------
// Kernel 2: radius ball query + select 33 nearest (lexicographic (d2, idx)).
// One wave per centroid, 4 centroids per block, shared pos-tile staging.
// ---------------------------------------------------------------------------
#define BQ_TILE 2048
#define BQ_CAP 1024
__global__ __launch_bounds__(256) void ballq_kernel(const float* __restrict__ pos,
    const int* __restrict__ idxg, int* __restrict__ nbr, int* __restrict__ cntsel) {
  __shared__ float xs[BQ_TILE], ys[BQ_TILE], zs[BQ_TILE];
  __shared__ float d2l[4 * BQ_CAP];
  __shared__ int   jl[4 * BQ_CAP];
  __shared__ int   cntL[4];
  const int t = threadIdx.x, lane = t & 63, wv = t >> 6;
  const int c = blockIdx.x * 4 + wv;
  const int b = c >> 12;            // c / 4096
  const int cbase = b * NPTS;
  if (t < 4) cntL[t] = 0;
  const int ci = idxg[c];
  const float cx = pos[ci * 3 + 0], cy = pos[ci * 3 + 1], cz = pos[ci * 3 + 2];
  __syncthreads();
  for (int T = 0; T < NPTS / BQ_TILE; ++T) {
    for (int s = t; s < BQ_TILE; s += 256) {
      int p = cbase + T * BQ_TILE + s;
      xs[s] = pos[p * 3 + 0]; ys[s] = pos[p * 3 + 1]; zs[s] = pos[p * 3 + 2];
    }
    __syncthreads();
    for (int s = lane; s < BQ_TILE; s += 64) {
      float dx = xs[s] - cx, dy = ys[s] - cy, dz = zs[s] - cz;
      float d2 = __fadd_rn(__fadd_rn(__fmul_rn(dx, dx), __fmul_rn(dy, dy)), __fmul_rn(dz, dz));
      if (d2 <= R2V) {
        int p = atomicAdd(&cntL[wv], 1);
        if (p < BQ_CAP) { d2l[wv * BQ_CAP + p] = d2; jl[wv * BQ_CAP + p] = T * BQ_TILE + s; }
      }
    }
    __syncthreads();
  }
  int n = min(cntL[wv], BQ_CAP);
  int ks = min(KNB, n);
  float lv = -1.0f; int lj = -1;
  for (int it = 0; it < ks; ++it) {
    float mv = 3.4e38f; int mj = 0x7fffffff;
    for (int s = lane; s < n; s += 64) {
      float v = d2l[wv * BQ_CAP + s]; int j = jl[wv * BQ_CAP + s];
      bool newer = (v > lv) || (v == lv && j > lj);
      if (newer && (v < mv || (v == mv && j < mj))) { mv = v; mj = j; }
    }
#pragma unroll
    for (int off = 32; off >= 1; off >>= 1) {
      float ov = __shfl_xor(mv, off, 64);
      int   oj = __shfl_xor(mj, off, 64);
      if (ov < mv || (ov == mv && oj < mj)) { mv = ov; mj = oj; }
    }
    if (lane == 0) nbr[c * NPAD + it] = cbase + mj;
    lv = mv; lj = mj;
  }
  if (lane == 0) cntsel[c] = ks;
}

// ---------------------------------------------------------------------------
// Kernel 3: fused layer1 (35->128) + layer2 (128->256) + masked max-agg.
// 2 centroids per block (80 edge rows, rows >= cnt zero/masked), 320 threads.
// ---------------------------------------------------------------------------
__global__ __launch_bounds__(320) void fused_kernel(const float* __restrict__ x,
    const float* __restrict__ pos, const int* __restrict__ idxg,
    const int* __restrict__ nbr, const int* __restrict__ cnts,
    const float* __restrict__ lw1, const float* __restrict__ lb1,
    const float* __restrict__ lw2, const float* __restrict__ lb2,
    float* __restrict__ agg) {
  __shared__ float h1s[80 * 132];      // 42.2 KB
  __shared__ float wt[16 * 256];       // 16 KB (union: wx stage 32x128 in phase1)
  __shared__ float xr[80 * 36];        // 11.5 KB
  __shared__ float wr[4 * 128];        // lw1 rows 32..34 + lb1
  __shared__ float dpx[80], dpy[80], dpz[80];
  __shared__ int   jg[80];
  __shared__ float pcs[6];
  __shared__ int   cns[2];
  __shared__ unsigned aggL[512];
  const int t = threadIdx.x;
  const int c0 = blockIdx.x * 2;

  // phase 0: metadata + small weights + agg init
  if (t < 2) {
    int c = c0 + t; int ci = idxg[c];
    pcs[t * 3 + 0] = pos[ci * 3 + 0];
    pcs[t * 3 + 1] = pos[ci * 3 + 1];
    pcs[t * 3 + 2] = pos[ci * 3 + 2];
    cns[t] = cnts[c];
  }
  for (int i = t; i < 512; i += 320) {
    wr[i] = (i < 384) ? lw1[32 * 128 + i] : lb1[i - 384];
    aggL[i] = 0u;
  }
  __syncthreads();
  if (t < 80) {
    int r = t; int cc = (r >= 40) ? 1 : 0; int e = r - cc * 40;
    int j = -1;
    if (e < cns[cc]) {
      j = nbr[(c0 + cc) * NPAD + e];
      dpx[r] = pos[j * 3 + 0] - pcs[cc * 3 + 0];
      dpy[r] = pos[j * 3 + 1] - pcs[cc * 3 + 1];
      dpz[r] = pos[j * 3 + 2] - pcs[cc * 3 + 2];
    } else { dpx[r] = 0.f; dpy[r] = 0.f; dpz[r] = 0.f; }
    jg[r] = j;
  }
  __syncthreads();
  // stage x rows (zero for invalid) + wx (= lw1[0:32][:]) into wt
  for (int i = t; i < 640; i += 320) {
    int r = i >> 3, q = i & 7;
    int j = jg[r];
    float4 v = make_float4(0.f, 0.f, 0.f, 0.f);
    if (j >= 0) v = *(const float4*)&x[j * CCH + q * 4];
    *(float4*)&xr[r * 36 + q * 4] = v;
  }
  for (int i = t; i < 1024; i += 320) {
    *(float4*)&wt[i * 4] = *(const float4*)&lw1[i * 4];
  }
  __syncthreads();

  // phase 1: h1 = relu(xr@wx + dpos@wr + lb1). tile 4 rows x 8 cols per thread.
  {
    const int rg = t >> 4;      // 0..19
    const int og = t & 15;      // 0..15
    float4 a0[4], a1[4];
#pragma unroll
    for (int i = 0; i < 4; ++i) { a0[i] = make_float4(0, 0, 0, 0); a1[i] = make_float4(0, 0, 0, 0); }
#pragma unroll
    for (int kq = 0; kq < 8; ++kq) {
      float4 xv[4];
#pragma unroll
      for (int i = 0; i < 4; ++i) xv[i] = *(const float4*)&xr[(rg * 4 + i) * 36 + kq * 4];
#pragma unroll
      for (int kk = 0; kk < 4; ++kk) {
        float4 w0 = *(const float4*)&wt[(kq * 4 + kk) * 128 + og * 8];
        float4 w1 = *(const float4*)&wt[(kq * 4 + kk) * 128 + og * 8 + 4];
#pragma unroll
        for (int i = 0; i < 4; ++i) {
          float s = get4(xv[i], kk);
          FMA4(a0[i], s, w0);
          FMA4(a1[i], s, w1);
        }
      }
    }
#pragma unroll
    for (int i = 0; i < 4; ++i) {
      int r = rg * 4 + i;
      float dx = dpx[r], dy = dpy[r], dz = dpz[r];
#pragma unroll
      for (int j = 0; j < 8; ++j) {
        int o = og * 8 + j;
        float v = (j < 4) ? get4(a0[i], j) : get4(a1[i], j - 4);
        v = v + dx * wr[o];
        v = v + dy * wr[128 + o];
        v = v + dz * wr[256 + o];
        v = v + wr[384 + o];
        h1s[r * 132 + o] = fmaxf(v, 0.0f);
      }
    }
  }
  __syncthreads();

  // phase 2: h2 = h1s[80x128] @ lw2[128x256], k-tiles of 16, tile 8x8/thread
  const int og2 = t & 31;   // cols og2*8
  const int eg = t >> 5;    // rows eg*8
  float4 c0v[8], c1v[8];
#pragma unroll
  for (int i = 0; i < 8; ++i) { c0v[i] = make_float4(0, 0, 0, 0); c1v[i] = make_float4(0, 0, 0, 0); }
  for (int kt = 0; kt < 8; ++kt) {
    __syncthreads();
    for (int i = t; i < 1024; i += 320) {
      *(float4*)&wt[i * 4] = *(const float4*)&lw2[kt * 4096 + i * 4];
    }
    __syncthreads();
#pragma unroll
    for (int kq = 0; kq < 4; ++kq) {
      float4 h4[8];
#pragma unroll
      for (int i = 0; i < 8; ++i)
        h4[i] = *(const float4*)&h1s[(eg * 8 + i) * 132 + kt * 16 + kq * 4];
#pragma unroll
      for (int kk = 0; kk < 4; ++kk) {
        float4 wa = *(const float4*)&wt[(kq * 4 + kk) * 256 + og2 * 8];
        float4 wb = *(const float4*)&wt[(kq * 4 + kk) * 256 + og2 * 8 + 4];
#pragma unroll
        for (int i = 0; i < 8; ++i) {
          float hv = get4(h4[i], kk);
          FMA4(c0v[i], hv, wa);
          FMA4(c1v[i], hv, wb);
        }
      }
    }
  }

  // phase 3: bias + relu + masked max into LDS (uint bits, values >= 0)
  {
    int cc = (eg >= 5) ? 1 : 0;
    int ebase = eg * 8 - cc * 40;
    int n = cns[cc];
#pragma unroll
    for (int j = 0; j < 8; ++j) {
      int o = og2 * 8 + j;
      float bias = lb2[o];
      float mx = -1.0f;
#pragma unroll
      for (int i = 0; i < 8; ++i) {
        if (ebase + i < n) {
          float v = ((j < 4) ? get4(c0v[i], j) : get4(c1v[i], j - 4)) + bias;
          v = fmaxf(v, 0.0f);
          mx = fmaxf(mx, v);
        }
      }
      if (mx >= 0.0f) atomicMax(&aggL[cc * 256 + o], __float_as_uint(mx));
    }
  }
  __syncthreads();
  for (int i = t; i < 512; i += 320) {
    agg[c0 * 256 + i] = __uint_as_float(aggL[i]);
  }
}

// ---------------------------------------------------------------------------
// Kernel 4: out = relu(agg @ gw1 + gb1). 64 rows x 256 cols per block.
// ---------------------------------------------------------------------------
__global__ __launch_bounds__(256) void l3_kernel(const float* __restrict__ agg,
    const float* __restrict__ gw1, const float* __restrict__ gb1,
    float* __restrict__ out) {
  __shared__ float at[32 * 68];
  __shared__ float wt[32 * 256];
  const int t = threadIdx.x;
  const int row0 = blockIdx.x * 64;
  const int og = t & 31, rg = t >> 5;
  float4 c0v[8], c1v[8];
#pragma unroll
  for (int i = 0; i < 8; ++i) { c0v[i] = make_float4(0, 0, 0, 0); c1v[i] = make_float4(0, 0, 0, 0); }
  for (int kt = 0; kt < 8; ++kt) {
    __syncthreads();
    for (int i = t; i < 2048; i += 256) {
      int k = i & 31, r = i >> 5;
      at[k * 68 + r] = agg[(row0 + r) * 256 + kt * 32 + k];
    }
    for (int i = t; i < 2048; i += 256) {
      *(float4*)&wt[i * 4] = *(const float4*)&gw1[kt * 8192 + i * 4];
    }
    __syncthreads();
#pragma unroll
    for (int kq = 0; kq < 8; ++kq) {
#pragma unroll
      for (int kk = 0; kk < 4; ++kk) {
        int k = kq * 4 + kk;
        float4 av0 = *(const float4*)&at[k * 68 + rg * 8];
        float4 av1 = *(const float4*)&at[k * 68 + rg * 8 + 4];
        float4 wa = *(const float4*)&wt[k * 256 + og * 8];
        float4 wb = *(const float4*)&wt[k * 256 + og * 8 + 4];
#pragma unroll
        for (int i = 0; i < 8; ++i) {
          float hv = (i < 4) ? get4(av0, i) : get4(av1, i - 4);
          FMA4(c0v[i], hv, wa);
          FMA4(c1v[i], hv, wb);
        }
      }
    }
  }
  float4 b0 = *(const float4*)&gb1[og * 8];
  float4 b1 = *(const float4*)&gb1[og * 8 + 4];
#pragma unroll
  for (int i = 0; i < 8; ++i) {
    float4 v0, v1;
    v0.x = fmaxf(c0v[i].x + b0.x, 0.f); v0.y = fmaxf(c0v[i].y + b0.y, 0.f);
    v0.z = fmaxf(c0v[i].z + b0.z, 0.f); v0.w = fmaxf(c0v[i].w + b0.w, 0.f);
    v1.x = fmaxf(c1v[i].x + b1.x, 0.f); v1.y = fmaxf(c1v[i].y + b1.y, 0.f);
    v1.z = fmaxf(c1v[i].z + b1.z, 0.f); v1.w = fmaxf(c1v[i].w + b1.w, 0.f);
    int row = row0 + rg * 8 + i;
    *(float4*)&out[row * 256 + og * 8] = v0;
    *(float4*)&out[row * 256 + og * 8 + 4] = v1;
  }
}

extern "C" void kernel_launch(void* const* d_in, const int* in_sizes, int n_in,
                              void* d_out, int out_size, void* d_ws, size_t ws_size,
                              hipStream_t stream) {
  (void)in_sizes; (void)n_in; (void)out_size; (void)ws_size;
  const float* x   = (const float*)d_in[0];
  const float* pos = (const float*)d_in[1];
  const float* lw1 = (const float*)d_in[3];
  const float* lb1 = (const float*)d_in[4];
  const float* lw2 = (const float*)d_in[5];
  const float* lb2 = (const float*)d_in[6];
  const float* gw1 = (const float*)d_in[7];
  const float* gb1 = (const float*)d_in[8];

  char* ws = (char*)d_ws;
  int*   idxg   = (int*)(ws + WS_IDX);
  int*   cnts   = (int*)(ws + WS_CNT);
  int*   nbr    = (int*)(ws + WS_NBR);
  float* agg    = (float*)(ws + WS_AGG);

  float* out0   = (float*)d_out;
  float* posd   = out0 + (size_t)M_TOT * HH3;
  float* batchf = posd + (size_t)M_TOT * 3;

  fps_kernel<<<dim3(NB), dim3(512), 0, stream>>>(pos, idxg, posd, batchf);
  ballq_kernel<<<dim3(M_TOT / 4), dim3(256), 0, stream>>>(pos, idxg, nbr, cnts);
  fused_kernel<<<dim3(M_TOT / 2), dim3(320), 0, stream>>>(x, pos, idxg, nbr, cnts,
                                                          lw1, lb1, lw2, lb2, agg);
  l3_kernel<<<dim3(M_TOT / 64), dim3(256), 0, stream>>>(agg, gw1, gb1, out0);
}

// Round 11
// 11287.711 us; speedup vs baseline: 1.0064x; 1.0064x over previous
//
#include <hip/hip_runtime.h>

#define NPTS 16384
#define NB 4
#define MPER 4096
#define M_TOT 16384
#define CCH 32
#define HH1 128
#define HH2 256
#define HH3 256
#define KNB 33
#define NPAD 36
#define R2V (0.2f*0.2f)

// ws layout (bytes)
#define WS_IDX   0                    // 16384 int
#define WS_CNT   (WS_IDX + 65536)     // 16384 int
#define WS_NBR   (WS_CNT + 65536)     // 16384*36 int
#define WS_AGG   (WS_NBR + 2359296)   // 16384*256 f32

static __device__ __forceinline__ float get4(const float4& v, int j) {
  return j == 0 ? v.x : j == 1 ? v.y : j == 2 ? v.z : v.w;
}

#define FMA4(acc_, s_, w_) { (acc_).x += (s_)*(w_).x; (acc_).y += (s_)*(w_).y; (acc_).z += (s_)*(w_).z; (acc_).w += (s_)*(w_).w; }

// ---------------------------------------------------------------------------
// Kernel 1: farthest point sampling. One block per cloud, 1024 threads,
// 16 points/thread (64 floats of state) — r8-r10 showed the allocator caps
// at ~104 VGPR (4-waves/EU target) and spills 32-pt/thread state to scratch
// no matter the source form; 16 pts/thread fits under the 128-reg cap.
// One barrier/iter, double-buffered LDS wave-partials (16 waves),
// LDS-broadcast + 4-step shfl_xor inter-wave reduce. Exact (non-FMA)
// distance math to match numpy rounding; argmax ties -> lowest index.
// ---------------------------------------------------------------------------
__global__ __launch_bounds__(1024, 4) void fps_kernel(const float* __restrict__ pos,
    int* __restrict__ idxg, float* __restrict__ posd, float* __restrict__ batchf) {
  const int b = blockIdx.x;
  const int t = threadIdx.x;          // 0..1023
  const int base = b * NPTS;
  const int lane = t & 63, wv = t >> 6;  // wv 0..15
  __shared__ float bufV[2][16];
  __shared__ int   bufI[2][16];

  float4 px0, px1, px2, px3;
  float4 py0, py1, py2, py3;
  float4 pz0, pz1, pz2, pz3;
  float4 md0, md1, md2, md3;

#define LD1(C_, PX_, PY_, PZ_, I0_) { \
    int p_ = base + (I0_) + t; \
    PX_.C_ = pos[p_ * 3 + 0]; PY_.C_ = pos[p_ * 3 + 1]; PZ_.C_ = pos[p_ * 3 + 2]; }
#define LD4(PX_, PY_, PZ_, G_) \
    LD1(x, PX_, PY_, PZ_, ((G_)*4+0)*1024) \
    LD1(y, PX_, PY_, PZ_, ((G_)*4+1)*1024) \
    LD1(z, PX_, PY_, PZ_, ((G_)*4+2)*1024) \
    LD1(w, PX_, PY_, PZ_, ((G_)*4+3)*1024)

  LD4(px0, py0, pz0, 0) LD4(px1, py1, pz1, 1)
  LD4(px2, py2, pz2, 2) LD4(px3, py3, pz3, 3)

  // Opaque keep: forbid rematerialization of the staged coordinates.
#define KEEP4(V_) asm volatile("" : "+v"((V_).x), "+v"((V_).y), "+v"((V_).z), "+v"((V_).w));
  KEEP4(px0) KEEP4(px1) KEEP4(px2) KEEP4(px3)
  KEEP4(py0) KEEP4(py1) KEEP4(py2) KEEP4(py3)
  KEEP4(pz0) KEEP4(pz1) KEEP4(pz2) KEEP4(pz3)

  float nx = pos[base * 3 + 0], ny = pos[base * 3 + 1], nz = pos[base * 3 + 2];
  if (t == 0) {
    idxg[b * MPER] = base;
    posd[(b * MPER) * 3 + 0] = nx;
    posd[(b * MPER) * 3 + 1] = ny;
    posd[(b * MPER) * 3 + 2] = nz;
    batchf[b * MPER] = (float)b;
  }

  float bv = -1.0f; int bi = 0;

#define INI1(C_, PX_, PY_, PZ_, MD_, I0_) { \
    float dx_ = PX_.C_ - nx, dy_ = PY_.C_ - ny, dz_ = PZ_.C_ - nz; \
    float d2_ = __fadd_rn(__fadd_rn(__fmul_rn(dx_, dx_), __fmul_rn(dy_, dy_)), __fmul_rn(dz_, dz_)); \
    MD_.C_ = d2_; \
    if (d2_ > bv) { bv = d2_; bi = (I0_) + t; } }
#define INI4(PX_, PY_, PZ_, MD_, G_) \
    INI1(x, PX_, PY_, PZ_, MD_, ((G_)*4+0)*1024) \
    INI1(y, PX_, PY_, PZ_, MD_, ((G_)*4+1)*1024) \
    INI1(z, PX_, PY_, PZ_, MD_, ((G_)*4+2)*1024) \
    INI1(w, PX_, PY_, PZ_, MD_, ((G_)*4+3)*1024)

  INI4(px0, py0, pz0, md0, 0) INI4(px1, py1, pz1, md1, 1)
  INI4(px2, py2, pz2, md2, 2) INI4(px3, py3, pz3, md3, 3)

#pragma unroll
  for (int off = 32; off >= 1; off >>= 1) {
    float ov = __shfl_xor(bv, off, 64);
    int   oi = __shfl_xor(bi, off, 64);
    if (ov > bv || (ov == bv && oi < bi)) { bv = ov; bi = oi; }
  }

#define UPD1(C_, PX_, PY_, PZ_, MD_, I0_) { \
    float dx_ = PX_.C_ - nx, dy_ = PY_.C_ - ny, dz_ = PZ_.C_ - nz; \
    float d2_ = __fadd_rn(__fadd_rn(__fmul_rn(dx_, dx_), __fmul_rn(dy_, dy_)), __fmul_rn(dz_, dz_)); \
    float m_ = fminf(MD_.C_, d2_); MD_.C_ = m_; \
    if (m_ > bv) { bv = m_; bi = (I0_) + t; } }
#define UPD4(PX_, PY_, PZ_, MD_, G_) \
    UPD1(x, PX_, PY_, PZ_, MD_, ((G_)*4+0)*1024) \
    UPD1(y, PX_, PY_, PZ_, MD_, ((G_)*4+1)*1024) \
    UPD1(z, PX_, PY_, PZ_, MD_, ((G_)*4+2)*1024) \
    UPD1(w, PX_, PY_, PZ_, MD_, ((G_)*4+3)*1024)

  for (int m = 1; m < MPER; ++m) {
    if (lane == 0) { bufV[m & 1][wv] = bv; bufI[m & 1][wv] = bi; }
    __syncthreads();
    // inter-wave reduce: LDS broadcast of 16 partials + 4-step xor reduce
    float v = bufV[m & 1][lane & 15];
    int   j = bufI[m & 1][lane & 15];
#pragma unroll
    for (int off = 8; off >= 1; off >>= 1) {
      float ov = __shfl_xor(v, off, 64);
      int   oj = __shfl_xor(j, off, 64);
      if (ov > v || (ov == v && oj < j)) { v = ov; j = oj; }
    }
    nx = pos[(base + j) * 3 + 0];
    ny = pos[(base + j) * 3 + 1];
    nz = pos[(base + j) * 3 + 2];
    if (t == 0) {
      idxg[b * MPER + m] = base + j;
      posd[(b * MPER + m) * 3 + 0] = nx;
      posd[(b * MPER + m) * 3 + 1] = ny;
      posd[(b * MPER + m) * 3 + 2] = nz;
      batchf[b * MPER + m] = (float)b;
    }
    bv = -1.0f; bi = 0;
    UPD4(px0, py0, pz0, md0, 0) UPD4(px1, py1, pz1, md1, 1)
    UPD4(px2, py2, pz2, md2, 2) UPD4(px3, py3, pz3, md3, 3)
#pragma unroll
    for (int off = 32; off >= 1; off >>= 1) {
      float ov = __shfl_xor(bv, off, 64);
      int   oi = __shfl_xor(bi, off, 64);
      if (ov > bv || (ov == bv && oi < bi)) { bv = ov; bi = oi; }
    }
  }
}

// ---------------------------------------------------------------------------
// Kernel 2: radius ball query + select 33 nearest (lexicographic (d2, idx)).
// One wave per centroid, 4 centroids per block, shared pos-tile staging.
// ---------------------------------------------------------------------------
#define BQ_TILE 2048
#define BQ_CAP 1024
__global__ __launch_bounds__(256) void ballq_kernel(const float* __restrict__ pos,
    const int* __restrict__ idxg, int* __restrict__ nbr, int* __restrict__ cntsel) {
  __shared__ float xs[BQ_TILE], ys[BQ_TILE], zs[BQ_TILE];
  __shared__ float d2l[4 * BQ_CAP];
  __shared__ int   jl[4 * BQ_CAP];
  __shared__ int   cntL[4];
  const int t = threadIdx.x, lane = t & 63, wv = t >> 6;
  const int c = blockIdx.x * 4 + wv;
  const int b = c >> 12;            // c / 4096
  const int cbase = b * NPTS;
  if (t < 4) cntL[t] = 0;
  const int ci = idxg[c];
  const float cx = pos[ci * 3 + 0], cy = pos[ci * 3 + 1], cz = pos[ci * 3 + 2];
  __syncthreads();
  for (int T = 0; T < NPTS / BQ_TILE; ++T) {
    for (int s = t; s < BQ_TILE; s += 256) {
      int p = cbase + T * BQ_TILE + s;
      xs[s] = pos[p * 3 + 0]; ys[s] = pos[p * 3 + 1]; zs[s] = pos[p * 3 + 2];
    }
    __syncthreads();
    for (int s = lane; s < BQ_TILE; s += 64) {
      float dx = xs[s] - cx, dy = ys[s] - cy, dz = zs[s] - cz;
      float d2 = __fadd_rn(__fadd_rn(__fmul_rn(dx, dx), __fmul_rn(dy, dy)), __fmul_rn(dz, dz));
      if (d2 <= R2V) {
        int p = atomicAdd(&cntL[wv], 1);
        if (p < BQ_CAP) { d2l[wv * BQ_CAP + p] = d2; jl[wv * BQ_CAP + p] = T * BQ_TILE + s; }
      }
    }
    __syncthreads();
  }
  int n = min(cntL[wv], BQ_CAP);
  int ks = min(KNB, n);
  float lv = -1.0f; int lj = -1;
  for (int it = 0; it < ks; ++it) {
    float mv = 3.4e38f; int mj = 0x7fffffff;
    for (int s = lane; s < n; s += 64) {
      float v = d2l[wv * BQ_CAP + s]; int j = jl[wv * BQ_CAP + s];
      bool newer = (v > lv) || (v == lv && j > lj);
      if (newer && (v < mv || (v == mv && j < mj))) { mv = v; mj = j; }
    }
#pragma unroll
    for (int off = 32; off >= 1; off >>= 1) {
      float ov = __shfl_xor(mv, off, 64);
      int   oj = __shfl_xor(mj, off, 64);
      if (ov < mv || (ov == mv && oj < mj)) { mv = ov; mj = oj; }
    }
    if (lane == 0) nbr[c * NPAD + it] = cbase + mj;
    lv = mv; lj = mj;
  }
  if (lane == 0) cntsel[c] = ks;
}

// ---------------------------------------------------------------------------
// Kernel 3: fused layer1 (35->128) + layer2 (128->256) + masked max-agg.
// 2 centroids per block (80 edge rows, rows >= cnt zero/masked), 320 threads.
// ---------------------------------------------------------------------------
__global__ __launch_bounds__(320) void fused_kernel(const float* __restrict__ x,
    const float* __restrict__ pos, const int* __restrict__ idxg,
    const int* __restrict__ nbr, const int* __restrict__ cnts,
    const float* __restrict__ lw1, const float* __restrict__ lb1,
    const float* __restrict__ lw2, const float* __restrict__ lb2,
    float* __restrict__ agg) {
  __shared__ float h1s[80 * 132];      // 42.2 KB
  __shared__ float wt[16 * 256];       // 16 KB (union: wx stage 32x128 in phase1)
  __shared__ float xr[80 * 36];        // 11.5 KB
  __shared__ float wr[4 * 128];        // lw1 rows 32..34 + lb1
  __shared__ float dpx[80], dpy[80], dpz[80];
  __shared__ int   jg[80];
  __shared__ float pcs[6];
  __shared__ int   cns[2];
  __shared__ unsigned aggL[512];
  const int t = threadIdx.x;
  const int c0 = blockIdx.x * 2;

  // phase 0: metadata + small weights + agg init
  if (t < 2) {
    int c = c0 + t; int ci = idxg[c];
    pcs[t * 3 + 0] = pos[ci * 3 + 0];
    pcs[t * 3 + 1] = pos[ci * 3 + 1];
    pcs[t * 3 + 2] = pos[ci * 3 + 2];
    cns[t] = cnts[c];
  }
  for (int i = t; i < 512; i += 320) {
    wr[i] = (i < 384) ? lw1[32 * 128 + i] : lb1[i - 384];
    aggL[i] = 0u;
  }
  __syncthreads();
  if (t < 80) {
    int r = t; int cc = (r >= 40) ? 1 : 0; int e = r - cc * 40;
    int j = -1;
    if (e < cns[cc]) {
      j = nbr[(c0 + cc) * NPAD + e];
      dpx[r] = pos[j * 3 + 0] - pcs[cc * 3 + 0];
      dpy[r] = pos[j * 3 + 1] - pcs[cc * 3 + 1];
      dpz[r] = pos[j * 3 + 2] - pcs[cc * 3 + 2];
    } else { dpx[r] = 0.f; dpy[r] = 0.f; dpz[r] = 0.f; }
    jg[r] = j;
  }
  __syncthreads();
  // stage x rows (zero for invalid) + wx (= lw1[0:32][:]) into wt
  for (int i = t; i < 640; i += 320) {
    int r = i >> 3, q = i & 7;
    int j = jg[r];
    float4 v = make_float4(0.f, 0.f, 0.f, 0.f);
    if (j >= 0) v = *(const float4*)&x[j * CCH + q * 4];
    *(float4*)&xr[r * 36 + q * 4] = v;
  }
  for (int i = t; i < 1024; i += 320) {
    *(float4*)&wt[i * 4] = *(const float4*)&lw1[i * 4];
  }
  __syncthreads();

  // phase 1: h1 = relu(xr@wx + dpos@wr + lb1). tile 4 rows x 8 cols per thread.
  {
    const int rg = t >> 4;      // 0..19
    const int og = t & 15;      // 0..15
    float4 a0[4], a1[4];
#pragma unroll
    for (int i = 0; i < 4; ++i) { a0[i] = make_float4(0, 0, 0, 0); a1[i] = make_float4(0, 0, 0, 0); }
#pragma unroll
    for (int kq = 0; kq < 8; ++kq) {
      float4 xv[4];
#pragma unroll
      for (int i = 0; i < 4; ++i) xv[i] = *(const float4*)&xr[(rg * 4 + i) * 36 + kq * 4];
#pragma unroll
      for (int kk = 0; kk < 4; ++kk) {
        float4 w0 = *(const float4*)&wt[(kq * 4 + kk) * 128 + og * 8];
        float4 w1 = *(const float4*)&wt[(kq * 4 + kk) * 128 + og * 8 + 4];
#pragma unroll
        for (int i = 0; i < 4; ++i) {
          float s = get4(xv[i], kk);
          FMA4(a0[i], s, w0);
          FMA4(a1[i], s, w1);
        }
      }
    }
#pragma unroll
    for (int i = 0; i < 4; ++i) {
      int r = rg * 4 + i;
      float dx = dpx[r], dy = dpy[r], dz = dpz[r];
#pragma unroll
      for (int j = 0; j < 8; ++j) {
        int o = og * 8 + j;
        float v = (j < 4) ? get4(a0[i], j) : get4(a1[i], j - 4);
        v = v + dx * wr[o];
        v = v + dy * wr[128 + o];
        v = v + dz * wr[256 + o];
        v = v + wr[384 + o];
        h1s[r * 132 + o] = fmaxf(v, 0.0f);
      }
    }
  }
  __syncthreads();

  // phase 2: h2 = h1s[80x128] @ lw2[128x256], k-tiles of 16, tile 8x8/thread
  const int og2 = t & 31;   // cols og2*8
  const int eg = t >> 5;    // rows eg*8
  float4 c0v[8], c1v[8];
#pragma unroll
  for (int i = 0; i < 8; ++i) { c0v[i] = make_float4(0, 0, 0, 0); c1v[i] = make_float4(0, 0, 0, 0); }
  for (int kt = 0; kt < 8; ++kt) {
    __syncthreads();
    for (int i = t; i < 1024; i += 320) {
      *(float4*)&wt[i * 4] = *(const float4*)&lw2[kt * 4096 + i * 4];
    }
    __syncthreads();
#pragma unroll
    for (int kq = 0; kq < 4; ++kq) {
      float4 h4[8];
#pragma unroll
      for (int i = 0; i < 8; ++i)
        h4[i] = *(const float4*)&h1s[(eg * 8 + i) * 132 + kt * 16 + kq * 4];
#pragma unroll
      for (int kk = 0; kk < 4; ++kk) {
        float4 wa = *(const float4*)&wt[(kq * 4 + kk) * 256 + og2 * 8];
        float4 wb = *(const float4*)&wt[(kq * 4 + kk) * 256 + og2 * 8 + 4];
#pragma unroll
        for (int i = 0; i < 8; ++i) {
          float hv = get4(h4[i], kk);
          FMA4(c0v[i], hv, wa);
          FMA4(c1v[i], hv, wb);
        }
      }
    }
  }

  // phase 3: bias + relu + masked max into LDS (uint bits, values >= 0)
  {
    int cc = (eg >= 5) ? 1 : 0;
    int ebase = eg * 8 - cc * 40;
    int n = cns[cc];
#pragma unroll
    for (int j = 0; j < 8; ++j) {
      int o = og2 * 8 + j;
      float bias = lb2[o];
      float mx = -1.0f;
#pragma unroll
      for (int i = 0; i < 8; ++i) {
        if (ebase + i < n) {
          float v = ((j < 4) ? get4(c0v[i], j) : get4(c1v[i], j - 4)) + bias;
          v = fmaxf(v, 0.0f);
          mx = fmaxf(mx, v);
        }
      }
      if (mx >= 0.0f) atomicMax(&aggL[cc * 256 + o], __float_as_uint(mx));
    }
  }
  __syncthreads();
  for (int i = t; i < 512; i += 320) {
    agg[c0 * 256 + i] = __uint_as_float(aggL[i]);
  }
}

// ---------------------------------------------------------------------------
// Kernel 4: out = relu(agg @ gw1 + gb1). 64 rows x 256 cols per block.
// ---------------------------------------------------------------------------
__global__ __launch_bounds__(256) void l3_kernel(const float* __restrict__ agg,
    const float* __restrict__ gw1, const float* __restrict__ gb1,
    float* __restrict__ out) {
  __shared__ float at[32 * 68];
  __shared__ float wt[32 * 256];
  const int t = threadIdx.x;
  const int row0 = blockIdx.x * 64;
  const int og = t & 31, rg = t >> 5;
  float4 c0v[8], c1v[8];
#pragma unroll
  for (int i = 0; i < 8; ++i) { c0v[i] = make_float4(0, 0, 0, 0); c1v[i] = make_float4(0, 0, 0, 0); }
  for (int kt = 0; kt < 8; ++kt) {
    __syncthreads();
    for (int i = t; i < 2048; i += 256) {
      int k = i & 31, r = i >> 5;
      at[k * 68 + r] = agg[(row0 + r) * 256 + kt * 32 + k];
    }
    for (int i = t; i < 2048; i += 256) {
      *(float4*)&wt[i * 4] = *(const float4*)&gw1[kt * 8192 + i * 4];
    }
    __syncthreads();
#pragma unroll
    for (int kq = 0; kq < 8; ++kq) {
#pragma unroll
      for (int kk = 0; kk < 4; ++kk) {
        int k = kq * 4 + kk;
        float4 av0 = *(const float4*)&at[k * 68 + rg * 8];
        float4 av1 = *(const float4*)&at[k * 68 + rg * 8 + 4];
        float4 wa = *(const float4*)&wt[k * 256 + og * 8];
        float4 wb = *(const float4*)&wt[k * 256 + og * 8 + 4];
#pragma unroll
        for (int i = 0; i < 8; ++i) {
          float hv = (i < 4) ? get4(av0, i) : get4(av1, i - 4);
          FMA4(c0v[i], hv, wa);
          FMA4(c1v[i], hv, wb);
        }
      }
    }
  }
  float4 b0 = *(const float4*)&gb1[og * 8];
  float4 b1 = *(const float4*)&gb1[og * 8 + 4];
#pragma unroll
  for (int i = 0; i < 8; ++i) {
    float4 v0, v1;
    v0.x = fmaxf(c0v[i].x + b0.x, 0.f); v0.y = fmaxf(c0v[i].y + b0.y, 0.f);
    v0.z = fmaxf(c0v[i].z + b0.z, 0.f); v0.w = fmaxf(c0v[i].w + b0.w, 0.f);
    v1.x = fmaxf(c1v[i].x + b1.x, 0.f); v1.y = fmaxf(c1v[i].y + b1.y, 0.f);
    v1.z = fmaxf(c1v[i].z + b1.z, 0.f); v1.w = fmaxf(c1v[i].w + b1.w, 0.f);
    int row = row0 + rg * 8 + i;
    *(float4*)&out[row * 256 + og * 8] = v0;
    *(float4*)&out[row * 256 + og * 8 + 4] = v1;
  }
}

extern "C" void kernel_launch(void* const* d_in, const int* in_sizes, int n_in,
                              void* d_out, int out_size, void* d_ws, size_t ws_size,
                              hipStream_t stream) {
  (void)in_sizes; (void)n_in; (void)out_size; (void)ws_size;
  const float* x   = (const float*)d_in[0];
  const float* pos = (const float*)d_in[1];
  const float* lw1 = (const float*)d_in[3];
  const float* lb1 = (const float*)d_in[4];
  const float* lw2 = (const float*)d_in[5];
  const float* lb2 = (const float*)d_in[6];
  const float* gw1 = (const float*)d_in[7];
  const float* gb1 = (const float*)d_in[8];

  char* ws = (char*)d_ws;
  int*   idxg   = (int*)(ws + WS_IDX);
  int*   cnts   = (int*)(ws + WS_CNT);
  int*   nbr    = (int*)(ws + WS_NBR);
  float* agg    = (float*)(ws + WS_AGG);

  float* out0   = (float*)d_out;
  float* posd   = out0 + (size_t)M_TOT * HH3;
  float* batchf = posd + (size_t)M_TOT * 3;

  fps_kernel<<<dim3(NB), dim3(1024), 0, stream>>>(pos, idxg, posd, batchf);
  ballq_kernel<<<dim3(M_TOT / 4), dim3(256), 0, stream>>>(pos, idxg, nbr, cnts);
  fused_kernel<<<dim3(M_TOT / 2), dim3(320), 0, stream>>>(x, pos, idxg, nbr, cnts,
                                                          lw1, lb1, lw2, lb2, agg);
  l3_kernel<<<dim3(M_TOT / 64), dim3(256), 0, stream>>>(agg, gw1, gb1, out0);
}